// Round 9
// baseline (361.797 us; speedup 1.0000x reference)
//
#include <hip/hip_runtime.h>
#include <hip/hip_bf16.h>
#include <cstdint>

#define LRELU_SLOPE 0.2f

typedef short bf16x8 __attribute__((ext_vector_type(8)));
typedef float f32x4  __attribute__((ext_vector_type(4)));

__device__ __forceinline__ float b2f(unsigned short u) {
  return __uint_as_float(((unsigned int)u) << 16);
}
__device__ __forceinline__ unsigned short f2b(float f) {  // RNE
  unsigned int u = __float_as_uint(f);
  return (unsigned short)((u + 0x7fff + ((u >> 16) & 1)) >> 16);
}

__device__ __forceinline__ void gload16(const void* g, void* l) {
  __builtin_amdgcn_global_load_lds(
      (const __attribute__((address_space(1))) unsigned int*)g,
      (__attribute__((address_space(3))) unsigned int*)l, 16, 0, 0);
}

// ---------------------------------------------- fused x->bf16 pad + csr_count
__global__ __launch_bounds__(256)
void prep_x_count(const float* __restrict__ x, unsigned short* __restrict__ o,
                  int M, int Mpad, const int* __restrict__ ei, int E, int Etot,
                  int* __restrict__ count) {
  const int i = blockIdx.x * 256 + threadIdx.x;
  if (i < Mpad * 64) {
    const int row = i >> 6;
    const int c4  = (i & 63) * 4;
    ushort4 v = make_ushort4(0, 0, 0, 0);
    if (row < M) {
      const float4 f = *(const float4*)&x[(size_t)row * 256 + c4];
      v = make_ushort4(f2b(f.x), f2b(f.y), f2b(f.z), f2b(f.w));
    }
    *(ushort4*)&o[(size_t)row * 256 + c4] = v;
  }
  if (i < Etot) {
    const int d = (i < E) ? ei[E + i] : (i - E);
    atomicAdd(&count[d], 1);
  }
}

// ------------------------------------- both weight transposes in one launch
__global__ __launch_bounds__(256)
void cvt_wts(const float* __restrict__ W1, const float* __restrict__ W2,
             unsigned short* __restrict__ W1T, unsigned short* __restrict__ W2T) {
  int j = blockIdx.x * 256 + threadIdx.x;
  if (j < 512 * 256) {
    const int n = j >> 8, k = j & 255;
    W1T[j] = f2b(W1[(size_t)k * 512 + n]);
  } else {
    j -= 512 * 256;
    const int n = j >> 9, k = j & 511;
    W2T[j] = f2b(W2[(size_t)k * 256 + n]);
  }
}

// ------------------------------------------------------------- CSR scan
__global__ __launch_bounds__(256)
void scan_blocksum(const int* __restrict__ count, int* __restrict__ bsum, int Nn) {
  const int i0 = blockIdx.x * 1024 + threadIdx.x * 4;
  int s = 0;
#pragma unroll
  for (int k = 0; k < 4; ++k) { const int i = i0 + k; if (i < Nn) s += count[i]; }
#pragma unroll
  for (int off = 1; off < 64; off <<= 1) s += __shfl_xor(s, off);
  __shared__ int ws[4];
  if ((threadIdx.x & 63) == 0) ws[threadIdx.x >> 6] = s;
  __syncthreads();
  if (threadIdx.x == 0) bsum[blockIdx.x] = ws[0] + ws[1] + ws[2] + ws[3];
}

__global__ __launch_bounds__(64)
void scan_top(const int* __restrict__ bsum, int* __restrict__ boff,
              int* __restrict__ rowptrN, int nb) {
  const int t = threadIdx.x;
  const int v = (t < nb) ? bsum[t] : 0;
  int incl = v;
#pragma unroll
  for (int off = 1; off < 64; off <<= 1) {
    const int u = __shfl_up(incl, off);
    if (t >= off) incl += u;
  }
  if (t < nb) boff[t] = incl - v;
  if (t == 63) *rowptrN = incl;
}

__global__ __launch_bounds__(256)
void scan_apply(const int* __restrict__ count, const int* __restrict__ boff,
                int* __restrict__ rowptr, int* __restrict__ cursor, int Nn) {
  const int t = threadIdx.x;
  const int lane = t & 63;
  const int w = t >> 6;
  const int i0 = blockIdx.x * 1024 + t * 4;
  int c[4]; int s = 0;
#pragma unroll
  for (int k = 0; k < 4; ++k) { const int i = i0 + k; c[k] = (i < Nn) ? count[i] : 0; s += c[k]; }
  int incl = s;
#pragma unroll
  for (int off = 1; off < 64; off <<= 1) {
    const int u = __shfl_up(incl, off);
    if (lane >= off) incl += u;
  }
  __shared__ int ws[4];
  if (lane == 63) ws[w] = incl;
  __syncthreads();
  int woff = 0;
  for (int k = 0; k < w; ++k) woff += ws[k];
  int base = boff[blockIdx.x] + woff + incl - s;
#pragma unroll
  for (int k = 0; k < 4; ++k) {
    const int i = i0 + k;
    if (i < Nn) { rowptr[i] = base; cursor[i] = base; base += c[k]; }
  }
}

__global__ __launch_bounds__(256)
void csr_scatter(const int* __restrict__ ei, int E, int Etot,
                 int* __restrict__ cursor, int* __restrict__ srcs,
                 int* __restrict__ dsts) {
  const int i = blockIdx.x * 256 + threadIdx.x;
  if (i >= Etot) return;
  const int s = (i < E) ? ei[i]     : (i - E);
  const int d = (i < E) ? ei[E + i] : (i - E);
  const int pos = atomicAdd(&cursor[d], 1);
  srcs[pos] = s;
  dsts[pos] = d;
}

// --------------------- persistent bf16 MFMA GEMM + fused attention-logit dots
// grid = 8 XCD * GRPX groups * NBCOL bcol-tiles blocks, all co-resident.
// Each block: one bcol-tile x [t0,t0+nT) brow-tiles, 3-buffer LDS rotation
// running across tile boundaries (epilogue overlaps next tile's staging).
// LDS slot hash rho(r)=(r^(r>>2))&3 -> 2-way max bank aliasing on ds_read_b128.
template<int KSTEPS, int NBCOL, int GRPX>
__global__ __launch_bounds__(256)
void gemm_bf16(const unsigned short* __restrict__ A,
               const unsigned short* __restrict__ BT,
               unsigned short* __restrict__ C, int M, int Nn, int K,
               const float* __restrict__ asrc, const float* __restrict__ adst,
               float* __restrict__ es, float* __restrict__ ed,
               int H, int lgC, int esPart, int TB) {
  __shared__ unsigned short As[3][128 * 32];
  __shared__ unsigned short Bs[3][128 * 32];
  const int tid  = threadIdx.x;
  const int lane = tid & 63;
  const int wave = tid >> 6;
  const int wm = wave >> 1, wn = wave & 1;
  // XCD-aware persistent decomposition
  const int bid = blockIdx.x;
  const int xcd = bid & 7;
  const int w   = bid >> 3;
  const int bcol_t = w % NBCOL;
  const int grp = xcd * GRPX + w / NBCOL;
  constexpr int G = 8 * GRPX * 1;
  const int q = TB / G, r = TB % G;
  const int t0 = grp * q + min(grp, r);
  const int nT = q + (grp < r ? 1 : 0);
  const int bcol = bcol_t * 128;
  // staging mapping: thread -> (row, k-slot), slot hashed by rho(row)
  const int srow  = tid >> 2;
  const int sslot = tid & 3;
  const int sswz  = sslot ^ ((srow ^ (srow >> 2)) & 3);
  const int ldsOff0 = srow * 32 + sslot * 8;
  const int ldsOff1 = (64 + srow) * 32 + sslot * 8;
  const size_t bB0 = (size_t)(bcol + srow) * K + sswz * 8;
  const size_t bB1 = (size_t)(bcol + 64 + srow) * K + sswz * 8;
  es += (size_t)bcol_t * esPart;
  ed += (size_t)bcol_t * esPart;
  // fragment read mapping
  const int u   = lane >> 4;
  const int r15 = lane & 15;
  const int sw  = u ^ ((r15 ^ (r15 >> 2)) & 3);
  // attention vectors for this bcol tile
  const int head = bcol >> lgC;
  float asv[4], adv[4];
#pragma unroll
  for (int n = 0; n < 4; ++n) {
    const int cc = bcol + wn * 64 + n * 16 + r15;
    asv[n] = asrc[cc];
    adv[n] = adst[cc];
  }

  auto stageA = [&](int buf, int tile, int ks) {
    const size_t base = (size_t)(tile * 128 + srow) * K + sswz * 8 + ks * 32;
    gload16(A + base, &As[buf][ldsOff0]);
    gload16(A + base + (size_t)64 * K, &As[buf][ldsOff1]);
  };
  auto stageB = [&](int buf, int ks) {
    gload16(BT + bB0 + ks * 32, &Bs[buf][ldsOff0]);
    gload16(BT + bB1 + ks * 32, &Bs[buf][ldsOff1]);
  };

  const int tot = nT * KSTEPS;
  stageA(0, t0, 0); stageB(0, 0);
  stageA(1, t0, 1); stageB(1, 1);

  f32x4 acc[4][4] = {};
  int cur = 0;
  for (int vs = 0; vs < tot; ++vs) {
    const int ks = vs % KSTEPS;
    // boundary steps (after an epilogue, or the last step) drain; steady
    // steps use counted vmcnt so 2 stages stay in flight across barriers.
    if (vs + 1 == tot || (ks == 0 && vs != 0))
      asm volatile("s_waitcnt vmcnt(0)" ::: "memory");
    else
      asm volatile("s_waitcnt vmcnt(4)" ::: "memory");
    __builtin_amdgcn_s_barrier();
    const int vs2 = vs + 2;
    if (vs2 < tot) {
      const int nb = (cur + 2 >= 3) ? cur - 1 : cur + 2;
      stageA(nb, t0 + vs2 / KSTEPS, vs2 % KSTEPS);
      stageB(nb, vs2 % KSTEPS);
    }
    bf16x8 af[4], bfv[4];
#pragma unroll
    for (int m = 0; m < 4; ++m) {
      const int row = wm * 64 + m * 16 + r15;
      af[m]  = *(const bf16x8*)&As[cur][row * 32 + sw * 8];
      const int col = wn * 64 + m * 16 + r15;
      bfv[m] = *(const bf16x8*)&Bs[cur][col * 32 + sw * 8];
    }
#pragma unroll
    for (int m = 0; m < 4; ++m)
#pragma unroll
      for (int n = 0; n < 4; ++n)
        acc[m][n] = __builtin_amdgcn_mfma_f32_16x16x32_bf16(
            af[m], bfv[n], acc[m][n], 0, 0, 0);
    if (ks == KSTEPS - 1) {
      // -------- epilogue for tile (overlaps next tile's staged loads) -----
      const int brow = (t0 + vs / KSTEPS) * 128;
#pragma unroll
      for (int m = 0; m < 4; ++m) {
        const int r0 = brow + wm * 64 + m * 16 + u * 4;
#pragma unroll
        for (int n = 0; n < 4; ++n) {
          const int cc = bcol + wn * 64 + n * 16 + r15;
#pragma unroll
          for (int rr = 0; rr < 4; ++rr)
            if (r0 + rr < M) C[(size_t)(r0 + rr) * Nn + cc] = f2b(acc[m][n][rr]);
        }
      }
#pragma unroll
      for (int m = 0; m < 4; ++m) {
#pragma unroll
        for (int rr = 0; rr < 4; ++rr) {
          float pes = 0.f, ped = 0.f;
#pragma unroll
          for (int n = 0; n < 4; ++n) {
            pes = fmaf(acc[m][n][rr], asv[n], pes);
            ped = fmaf(acc[m][n][rr], adv[n], ped);
          }
#pragma unroll
          for (int off = 1; off < 16; off <<= 1) {
            pes += __shfl_xor(pes, off);
            ped += __shfl_xor(ped, off);
          }
          if (r15 == 0) {
            const int row = brow + wm * 64 + m * 16 + u * 4 + rr;
            if (row < M) {
              unsafeAtomicAdd(&es[row * H + head], pes);
              unsafeAtomicAdd(&ed[row * H + head], ped);
            }
          }
        }
      }
#pragma unroll
      for (int m = 0; m < 4; ++m)
#pragma unroll
        for (int n = 0; n < 4; ++n)
          acc[m][n] = (f32x4){0.f, 0.f, 0.f, 0.f};
    }
    cur = (cur + 1 == 3) ? 0 : cur + 1;
  }
}

// ------------------- edge-parallel softmax numerator (CSR order), NO atomics
template<int H>
__global__ __launch_bounds__(256)
void ex_compute(const int* __restrict__ srcs, const int* __restrict__ dsts,
                const float* __restrict__ es, const float* __restrict__ ed,
                float* __restrict__ exCSR, int Etot, int pN) {
  const int p = blockIdx.x * 256 + threadIdx.x;
  if (p >= Etot) return;
  const int sN = srcs[p], dN = dsts[p];
  if constexpr (H == 4) {
    const float4 a = *(const float4*)&es[sN * 4];
    const float4 b = *(const float4*)&ed[dN * 4];
    float e0 = a.x + b.x, e1 = a.y + b.y, e2 = a.z + b.z, e3 = a.w + b.w;
    e0 = (e0 > 0.f) ? e0 : LRELU_SLOPE * e0;
    e1 = (e1 > 0.f) ? e1 : LRELU_SLOPE * e1;
    e2 = (e2 > 0.f) ? e2 : LRELU_SLOPE * e2;
    e3 = (e3 > 0.f) ? e3 : LRELU_SLOPE * e3;
    *(float4*)&exCSR[p * 4] =
        make_float4(__expf(e0), __expf(e1), __expf(e2), __expf(e3));
  } else {
    float e = (es[sN] + es[pN + sN]) + (ed[dN] + ed[pN + dN]);
    e = (e > 0.f) ? e : LRELU_SLOPE * e;
    exCSR[p] = __expf(e);
  }
}

// ---------------------- gather GAT aggregation + fused bias/LayerNorm(/ReLU)
template<int H, int C, bool RELU, bool BFOUT>
__global__ __launch_bounds__(256)
void gat_agg_ln(const int* __restrict__ rowptr, const int* __restrict__ srcs,
                const float* __restrict__ exCSR,
                const unsigned short* __restrict__ h,
                const float* __restrict__ bias, const float* __restrict__ lng,
                const float* __restrict__ lnb, unsigned short* __restrict__ obf,
                float* __restrict__ of32, int Nn) {
  constexpr int HC = H * C;
  constexpr int F  = HC / 64;
  const int wave = threadIdx.x >> 6;
  const int lane = threadIdx.x & 63;
  const int n = blockIdx.x * 4 + wave;
  if (n >= Nn) return;
  const int beg = rowptr[n];
  const int deg = rowptr[n + 1] - beg;
  const int hl = (lane * F) / C;

  float dsum = 0.f;
  if constexpr (H == 4) {
    for (int it = lane; it < deg * 4; it += 64) dsum += exCSR[beg * 4 + it];
#pragma unroll
    for (int off = 4; off < 64; off <<= 1) dsum += __shfl_xor(dsum, off);
    dsum = __shfl(dsum, hl);
  } else {
    for (int it = lane; it < deg; it += 64) dsum += exCSR[beg + it];
#pragma unroll
    for (int off = 1; off < 64; off <<= 1) dsum += __shfl_xor(dsum, off);
  }
  const float inv_s = 1.0f / (dsum + 1e-16f);

  float acc[F];
#pragma unroll
  for (int i = 0; i < F; ++i) acc[i] = 0.f;

  auto fma_rows = [&](const ushort4* v0, const ushort4* v1, const float* a, int cnt) {
    for (int q = 0; q < cnt; ++q) {
      acc[0] = fmaf(b2f(v0[q].x), a[q], acc[0]);
      acc[1] = fmaf(b2f(v0[q].y), a[q], acc[1]);
      acc[2] = fmaf(b2f(v0[q].z), a[q], acc[2]);
      acc[3] = fmaf(b2f(v0[q].w), a[q], acc[3]);
      if constexpr (F == 8) {
        acc[4] = fmaf(b2f(v1[q].x), a[q], acc[4]);
        acc[5] = fmaf(b2f(v1[q].y), a[q], acc[5]);
        acc[6] = fmaf(b2f(v1[q].z), a[q], acc[6]);
        acc[7] = fmaf(b2f(v1[q].w), a[q], acc[7]);
      }
    }
  };

  int j = 0;
  for (; j + 4 <= deg; j += 4) {
    int s4[4];
    float a4[4];
#pragma unroll
    for (int q = 0; q < 4; ++q) s4[q] = srcs[beg + j + q];
#pragma unroll
    for (int q = 0; q < 4; ++q) a4[q] = exCSR[(beg + j + q) * H + hl] * inv_s;
    ushort4 v0[4], v1[4];
#pragma unroll
    for (int q = 0; q < 4; ++q) {
      const unsigned short* hp = &h[(size_t)s4[q] * HC + lane * F];
      v0[q] = *(const ushort4*)hp;
      if constexpr (F == 8) v1[q] = *(const ushort4*)(hp + 4);
    }
    fma_rows(v0, v1, a4, 4);
  }
  for (; j < deg; ++j) {
    const int src = srcs[beg + j];
    const float a = exCSR[(beg + j) * H + hl] * inv_s;
    const unsigned short* hp = &h[(size_t)src * HC + lane * F];
    ushort4 v0 = *(const ushort4*)hp, v1;
    if constexpr (F == 8) v1 = *(const ushort4*)(hp + 4);
    fma_rows(&v0, &v1, &a, 1);
  }

#pragma unroll
  for (int i = 0; i < F; i += 4) {
    const float4 bb = *(const float4*)&bias[lane * F + i];
    acc[i + 0] += bb.x; acc[i + 1] += bb.y;
    acc[i + 2] += bb.z; acc[i + 3] += bb.w;
  }
  float sum = 0.f, sq = 0.f;
#pragma unroll
  for (int i = 0; i < F; ++i) { sum += acc[i]; sq += acc[i] * acc[i]; }
#pragma unroll
  for (int off = 1; off < 64; off <<= 1) {
    sum += __shfl_xor(sum, off);
    sq  += __shfl_xor(sq, off);
  }
  const float mu  = sum / HC;
  const float var = sq / HC - mu * mu;
  const float r   = rsqrtf(var + 1e-5f);
  float y[F];
#pragma unroll
  for (int i = 0; i < F; i += 4) {
    const float4 gg = *(const float4*)&lng[lane * F + i];
    const float4 bl = *(const float4*)&lnb[lane * F + i];
    y[i + 0] = (acc[i + 0] - mu) * r * gg.x + bl.x;
    y[i + 1] = (acc[i + 1] - mu) * r * gg.y + bl.y;
    y[i + 2] = (acc[i + 2] - mu) * r * gg.z + bl.z;
    y[i + 3] = (acc[i + 3] - mu) * r * gg.w + bl.w;
  }
  if constexpr (RELU) {
#pragma unroll
    for (int i = 0; i < F; ++i) y[i] = fmaxf(y[i], 0.f);
  }
  if constexpr (BFOUT) {
    unsigned short* op = &obf[(size_t)n * HC + lane * F];
    *(ushort4*)op = make_ushort4(f2b(y[0]), f2b(y[1]), f2b(y[2]), f2b(y[3]));
    if constexpr (F == 8)
      *(ushort4*)(op + 4) = make_ushort4(f2b(y[4]), f2b(y[5]), f2b(y[6]), f2b(y[7]));
  } else {
    float* op = &of32[(size_t)n * HC + lane * F];
    *(float4*)op = make_float4(y[0], y[1], y[2], y[3]);
    if constexpr (F == 8)
      *(float4*)(op + 4) = make_float4(y[4], y[5], y[6], y[7]);
  }
}

// ---------------------------------------------------------- global mean pool
__global__ __launch_bounds__(256)
void pool_partial(const unsigned short* __restrict__ x, const int* __restrict__ batch,
                  float* __restrict__ tmp, int* __restrict__ cnt, int Nn) {
  const int r0 = blockIdx.x * 64;
  const int rend = min(r0 + 64, Nn);
  const int t = threadIdx.x;
  float acc = 0.f;
  int cur = batch[r0];
  int seglen = 0;
  for (int r = r0; r < rend; ++r) {
    const int g = batch[r];
    if (g != cur) {
      unsafeAtomicAdd(&tmp[cur * 256 + t], acc);
      if (t == 0) atomicAdd(&cnt[cur], seglen);
      acc = 0.f; seglen = 0; cur = g;
    }
    acc += b2f(x[(size_t)r * 256 + t]);
    ++seglen;
  }
  unsafeAtomicAdd(&tmp[cur * 256 + t], acc);
  if (t == 0) atomicAdd(&cnt[cur], seglen);
}

__global__ __launch_bounds__(256)
void pool_final(const float* __restrict__ tmp, const int* __restrict__ cnt,
                float* __restrict__ out) {
  const int g = blockIdx.x;
  const int t = threadIdx.x;
  out[g * 256 + t] = tmp[g * 256 + t] / fmaxf((float)cnt[g], 1.f);
}

// ---------------------------------------------------------------------------
extern "C" void kernel_launch(void* const* d_in, const int* in_sizes, int n_in,
                              void* d_out, int out_size, void* d_ws, size_t ws_size,
                              hipStream_t stream) {
  const float* x    = (const float*)d_in[0];
  const int*   ei   = (const int*)d_in[1];
  const int*   batch= (const int*)d_in[2];
  const float* W1   = (const float*)d_in[3];
  const float* as1  = (const float*)d_in[4];
  const float* ad1  = (const float*)d_in[5];
  const float* b1   = (const float*)d_in[6];
  const float* g1   = (const float*)d_in[7];
  const float* be1  = (const float*)d_in[8];
  const float* W2   = (const float*)d_in[9];
  const float* as2  = (const float*)d_in[10];
  const float* ad2  = (const float*)d_in[11];
  const float* b2   = (const float*)d_in[12];
  const float* g2   = (const float*)d_in[13];
  const float* be2  = (const float*)d_in[14];

  const int N    = in_sizes[0] / 256;   // 50000
  const int E    = in_sizes[1] / 2;     // 400000
  const int Etot = E + N;
  const int Mpad = ((N + 127) / 128) * 128;   // 50048
  const int TB   = Mpad / 128;                // 391 brow tiles
  const int NB   = (N + 1023) / 1024;         // scan blocks (49)

  // ---------------- workspace layout ----------------
  float* ws = (float*)d_ws;
  unsigned short* out2 = (unsigned short*)ws;          // N*256 bf16
  unsigned short* A2bf = out2 + (size_t)N * 256;       // Mpad*512 bf16
  unsigned short* A1bf = A2bf;                         // Mpad*256 bf16
  unsigned short* h1bf = A2bf + (size_t)Mpad * 512;    // N*512 bf16 (h2bf aliases)
  unsigned short* W1T  = h1bf + (size_t)N * 512;       // 512*256 bf16
  unsigned short* W2T  = W1T + 512 * 256;              // 256*512 bf16
  float* es1 = (float*)(W2T + 512 * 256);              // N*4
  float* ed1 = es1 + (size_t)N * 4;                    // N*4
  float* es2 = ed1 + (size_t)N * 4;                    // 2N (per-bcol partials)
  float* ed2 = es2 + (size_t)N * 2;                    // 2N
  int* count  = (int*)(ed2 + (size_t)N * 2);           // N
  int* rowptr = count + N;                             // N+1 (+pad)
  int* cursor = rowptr + N + 4;                        // N
  int* srcs   = cursor + N;                            // Etot
  int* dsts   = srcs + Etot;                           // Etot
  float* exCSR = (float*)(dsts + Etot);                // Etot*4
  float* ptmp = exCSR + (size_t)Etot * 4;              // 64*256
  int*   pcnt = (int*)(ptmp + 64 * 256);               // 64
  int*   bsum = pcnt + 64;                             // NB
  int*   boff = bsum + 64;                             // NB
  unsigned short* h2bf = h1bf;

  const int eb = (Etot + 255) / 256;

  // ---- zero-init ----
  hipMemsetAsync(es1, 0, (size_t)N * 13 * 4, stream);
  hipMemsetAsync(ptmp, 0, (size_t)(64 * 256 + 64) * 4, stream);
  hipMemsetAsync(A2bf + (size_t)N * 512, 0, (size_t)(Mpad - N) * 512 * 2, stream);

  // ---- prep: x->bf16 pad + degree count, weight transposes ----
  prep_x_count<<<(Mpad * 64 + 255) / 256, 256, 0, stream>>>(
      x, A1bf, N, Mpad, ei, E, Etot, count);
  cvt_wts<<<(2 * 512 * 256 + 255) / 256, 256, 0, stream>>>(W1, W2, W1T, W2T);

  // ---- CSR build ----
  scan_blocksum<<<NB, 256, 0, stream>>>(count, bsum, N);
  scan_top<<<1, 64, 0, stream>>>(bsum, boff, &rowptr[N], NB);
  scan_apply<<<NB, 256, 0, stream>>>(count, boff, rowptr, cursor, N);
  csr_scatter<<<eb, 256, 0, stream>>>(ei, E, Etot, cursor, srcs, dsts);

  // ---- layer 1: GATConv(256 -> 4x128) + LN + ReLU ----
  gemm_bf16<8, 4, 24><<<768, 256, 0, stream>>>(
      A1bf, W1T, h1bf, N, 512, 256, as1, ad1, es1, ed1, 4, 7, 0, TB);
  ex_compute<4><<<eb, 256, 0, stream>>>(srcs, dsts, es1, ed1, exCSR, Etot, 0);
  gat_agg_ln<4, 128, true, true><<<(N + 3) / 4, 256, 0, stream>>>(
      rowptr, srcs, exCSR, h1bf, b1, g1, be1, A2bf, nullptr, N);

  // ---- layer 2: GATConv(512 -> 1x256) + LN ----
  gemm_bf16<16, 2, 32><<<512, 256, 0, stream>>>(
      A2bf, W2T, h2bf, N, 256, 512, as2, ad2, es2, ed2, 1, 8, N, TB);
  ex_compute<1><<<eb, 256, 0, stream>>>(srcs, dsts, es2, ed2, exCSR, Etot, N);
  gat_agg_ln<1, 256, false, true><<<(N + 3) / 4, 256, 0, stream>>>(
      rowptr, srcs, exCSR, h2bf, b2, g2, be2, out2, nullptr, N);

  // ---- global mean pool ----
  pool_partial<<<(N + 63) / 64, 256, 0, stream>>>(out2, batch, ptmp, pcnt, N);
  pool_final<<<64, 256, 0, stream>>>(ptmp, pcnt, (float*)d_out);
}

// Round 10
// 353.104 us; speedup vs baseline: 1.0246x; 1.0246x over previous
//
#include <hip/hip_runtime.h>
#include <hip/hip_bf16.h>
#include <cstdint>

#define LRELU_SLOPE 0.2f

typedef short bf16x8 __attribute__((ext_vector_type(8)));
typedef float f32x4  __attribute__((ext_vector_type(4)));

__device__ __forceinline__ float b2f(unsigned short u) {
  return __uint_as_float(((unsigned int)u) << 16);
}
__device__ __forceinline__ unsigned short f2b(float f) {  // RNE
  unsigned int u = __float_as_uint(f);
  return (unsigned short)((u + 0x7fff + ((u >> 16) & 1)) >> 16);
}

__device__ __forceinline__ void gload16(const void* g, void* l) {
  __builtin_amdgcn_global_load_lds(
      (const __attribute__((address_space(1))) unsigned int*)g,
      (__attribute__((address_space(3))) unsigned int*)l, 16, 0, 0);
}

// ---------------------------------------------- fused x->bf16 pad + csr_count
__global__ __launch_bounds__(256)
void prep_x_count(const float* __restrict__ x, unsigned short* __restrict__ o,
                  int M, int Mpad, const int* __restrict__ ei, int E, int Etot,
                  int* __restrict__ count) {
  const int i = blockIdx.x * 256 + threadIdx.x;
  if (i < Mpad * 64) {
    const int row = i >> 6;
    const int c4  = (i & 63) * 4;
    ushort4 v = make_ushort4(0, 0, 0, 0);
    if (row < M) {
      const float4 f = *(const float4*)&x[(size_t)row * 256 + c4];
      v = make_ushort4(f2b(f.x), f2b(f.y), f2b(f.z), f2b(f.w));
    }
    *(ushort4*)&o[(size_t)row * 256 + c4] = v;
  }
  if (i < Etot) {
    const int d = (i < E) ? ei[E + i] : (i - E);
    atomicAdd(&count[d], 1);
  }
}

// ------------------------------------- both weight transposes in one launch
__global__ __launch_bounds__(256)
void cvt_wts(const float* __restrict__ W1, const float* __restrict__ W2,
             unsigned short* __restrict__ W1T, unsigned short* __restrict__ W2T) {
  int j = blockIdx.x * 256 + threadIdx.x;
  if (j < 512 * 256) {
    const int n = j >> 8, k = j & 255;
    W1T[j] = f2b(W1[(size_t)k * 512 + n]);
  } else {
    j -= 512 * 256;
    const int n = j >> 9, k = j & 511;
    W2T[j] = f2b(W2[(size_t)k * 256 + n]);
  }
}

// ------------------------------------------------------------- CSR scan
__global__ __launch_bounds__(256)
void scan_blocksum(const int* __restrict__ count, int* __restrict__ bsum, int Nn) {
  const int i0 = blockIdx.x * 1024 + threadIdx.x * 4;
  int s = 0;
#pragma unroll
  for (int k = 0; k < 4; ++k) { const int i = i0 + k; if (i < Nn) s += count[i]; }
#pragma unroll
  for (int off = 1; off < 64; off <<= 1) s += __shfl_xor(s, off);
  __shared__ int ws[4];
  if ((threadIdx.x & 63) == 0) ws[threadIdx.x >> 6] = s;
  __syncthreads();
  if (threadIdx.x == 0) bsum[blockIdx.x] = ws[0] + ws[1] + ws[2] + ws[3];
}

__global__ __launch_bounds__(64)
void scan_top(const int* __restrict__ bsum, int* __restrict__ boff,
              int* __restrict__ rowptrN, int nb) {
  const int t = threadIdx.x;
  const int v = (t < nb) ? bsum[t] : 0;
  int incl = v;
#pragma unroll
  for (int off = 1; off < 64; off <<= 1) {
    const int u = __shfl_up(incl, off);
    if (t >= off) incl += u;
  }
  if (t < nb) boff[t] = incl - v;
  if (t == 63) *rowptrN = incl;
}

__global__ __launch_bounds__(256)
void scan_apply(const int* __restrict__ count, const int* __restrict__ boff,
                int* __restrict__ rowptr, int* __restrict__ cursor, int Nn) {
  const int t = threadIdx.x;
  const int lane = t & 63;
  const int w = t >> 6;
  const int i0 = blockIdx.x * 1024 + t * 4;
  int c[4]; int s = 0;
#pragma unroll
  for (int k = 0; k < 4; ++k) { const int i = i0 + k; c[k] = (i < Nn) ? count[i] : 0; s += c[k]; }
  int incl = s;
#pragma unroll
  for (int off = 1; off < 64; off <<= 1) {
    const int u = __shfl_up(incl, off);
    if (lane >= off) incl += u;
  }
  __shared__ int ws[4];
  if (lane == 63) ws[w] = incl;
  __syncthreads();
  int woff = 0;
  for (int k = 0; k < w; ++k) woff += ws[k];
  int base = boff[blockIdx.x] + woff + incl - s;
#pragma unroll
  for (int k = 0; k < 4; ++k) {
    const int i = i0 + k;
    if (i < Nn) { rowptr[i] = base; cursor[i] = base; base += c[k]; }
  }
}

__global__ __launch_bounds__(256)
void csr_scatter(const int* __restrict__ ei, int E, int Etot,
                 int* __restrict__ cursor, int* __restrict__ srcs,
                 int* __restrict__ dsts) {
  const int i = blockIdx.x * 256 + threadIdx.x;
  if (i >= Etot) return;
  const int s = (i < E) ? ei[i]     : (i - E);
  const int d = (i < E) ? ei[E + i] : (i - E);
  const int pos = atomicAdd(&cursor[d], 1);
  srcs[pos] = s;
  dsts[pos] = d;
}

// -------------------- B-resident bf16 MFMA GEMM + fused attention-logit dots
// B-panel (BN x K, 64 KB) staged to LDS once (XOR-swizzled via inverse-swz
// source, linear gload_lds dest). K-loop is barrier-free: A streamed
// global->VGPR (1-step ping-pong), B from static LDS, 16 MFMA/step/wave.
// Epilogue bounces C through LDS for coalesced 16B stores.
template<int BM, int BN, int WN, int K2, int KSTEPS>
__global__ __launch_bounds__(256)
void gemm_bres(const unsigned short* __restrict__ A,
               const unsigned short* __restrict__ BT,
               unsigned short* __restrict__ C, int M, int Nn,
               const float* __restrict__ asrc, const float* __restrict__ adst,
               float* __restrict__ es, float* __restrict__ ed,
               int H, int lgC, int esPart) {
  __shared__ __align__(16) unsigned char lds[65536];   // BN*K2 == 64 KB
  const int tid  = threadIdx.x;
  const int lane = tid & 63;
  const int wid  = tid >> 6;
  const int wm = (WN == 2) ? (wid >> 1) : wid;
  const int wn = (WN == 2) ? (wid & 1) : 0;
  const int brow = blockIdx.y * BM;
  const int bcol = blockIdx.x * BN;
  const int u = lane >> 4, r15 = lane & 15;

  // ---- stage B tile into LDS (linear dest, inverse-swizzled source) ----
  const char* Bb = (const char*)BT;
#pragma unroll
  for (int i = 0; i < 16; ++i) {
    const int b = (i * 256 + tid) * 16;
    const int col = b / K2;
    const int kb = (b & (K2 - 1)) ^ ((col & 7) << 4);
    gload16(Bb + (size_t)(bcol + col) * K2 + kb, &lds[b]);
  }
  // A fragment pointers (per m): row-major, 16B chunk per lane, +64B per step
  const char* aptr[4];
#pragma unroll
  for (int m = 0; m < 4; ++m)
    aptr[m] = (const char*)A +
              (size_t)(brow + wm * 64 + m * 16 + r15) * K2 + u * 16;
  int bbase[4], bsc[4];
#pragma unroll
  for (int n = 0; n < 4; ++n) {
    const int col = wn * 64 + n * 16 + r15;
    bbase[n] = col * K2;
    bsc[n]   = (col & 7) << 4;
  }
  asm volatile("s_waitcnt vmcnt(0)" ::: "memory");
  __builtin_amdgcn_s_barrier();

  f32x4 acc[4][4] = {};
  bf16x8 a0[4], a1[4];
#pragma unroll
  for (int m = 0; m < 4; ++m) a0[m] = *(const bf16x8*)(aptr[m]);
#pragma unroll
  for (int ks = 0; ks < KSTEPS; ++ks) {
    if (ks + 1 < KSTEPS) {
#pragma unroll
      for (int m = 0; m < 4; ++m)
        ((ks & 1) ? a0 : a1)[m] = *(const bf16x8*)(aptr[m] + (ks + 1) * 64);
    }
    bf16x8 bfv[4];
#pragma unroll
    for (int n = 0; n < 4; ++n)
      bfv[n] = *(const bf16x8*)&lds[bbase[n] + ((ks * 64 + u * 16) ^ bsc[n])];
#pragma unroll
    for (int m = 0; m < 4; ++m)
#pragma unroll
      for (int n = 0; n < 4; ++n)
        acc[m][n] = __builtin_amdgcn_mfma_f32_16x16x32_bf16(
            ((ks & 1) ? a1 : a0)[m], bfv[n], acc[m][n], 0, 0, 0);
  }

  // ---- epilogue: acc -> LDS (bf16) -> coalesced stores ----
  __builtin_amdgcn_s_barrier();          // all waves done reading B from LDS
  constexpr int CP = BN * 2 + 16;        // padded row pitch (16B-aligned)
#pragma unroll
  for (int m = 0; m < 4; ++m)
#pragma unroll
    for (int n = 0; n < 4; ++n) {
      const int col = wn * 64 + n * 16 + r15;
#pragma unroll
      for (int rr = 0; rr < 4; ++rr) {
        const int row = wm * 64 + m * 16 + u * 4 + rr;
        *(unsigned short*)&lds[row * CP + col * 2] = f2b(acc[m][n][rr]);
      }
    }
  __builtin_amdgcn_s_barrier();
#pragma unroll
  for (int i = 0; i < BM * BN * 2 / (256 * 16); ++i) {
    const int idx = (i * 256 + tid) * 16;
    const int row = idx / (BN * 2);
    const int cb  = idx % (BN * 2);
    const int grow = brow + row;
    if (grow < M)
      *(float4*)((char*)C + ((size_t)grow * Nn + bcol) * 2 + cb) =
          *(const float4*)&lds[row * CP + cb];
  }

  // ---- fused attention logits: es/ed[row,head] += sum_cols h*a ----
  es += (size_t)blockIdx.x * esPart;
  ed += (size_t)blockIdx.x * esPart;
  const int head = bcol >> lgC;
  float asv[4], adv[4];
#pragma unroll
  for (int n = 0; n < 4; ++n) {
    const int cc = bcol + wn * 64 + n * 16 + r15;
    asv[n] = asrc[cc];
    adv[n] = adst[cc];
  }
#pragma unroll
  for (int m = 0; m < 4; ++m) {
#pragma unroll
    for (int rr = 0; rr < 4; ++rr) {
      float pes = 0.f, ped = 0.f;
#pragma unroll
      for (int n = 0; n < 4; ++n) {
        pes = fmaf(acc[m][n][rr], asv[n], pes);
        ped = fmaf(acc[m][n][rr], adv[n], ped);
      }
#pragma unroll
      for (int off = 1; off < 16; off <<= 1) {
        pes += __shfl_xor(pes, off);
        ped += __shfl_xor(ped, off);
      }
      if (r15 == 0) {
        const int row = brow + wm * 64 + m * 16 + u * 4 + rr;
        if (row < M) {
          unsafeAtomicAdd(&es[row * H + head], pes);
          unsafeAtomicAdd(&ed[row * H + head], ped);
        }
      }
    }
  }
}

// ------------------- edge-parallel softmax numerator (CSR order), NO atomics
template<int H>
__global__ __launch_bounds__(256)
void ex_compute(const int* __restrict__ srcs, const int* __restrict__ dsts,
                const float* __restrict__ es, const float* __restrict__ ed,
                float* __restrict__ exCSR, int Etot, int pN) {
  const int p = blockIdx.x * 256 + threadIdx.x;
  if (p >= Etot) return;
  const int sN = srcs[p], dN = dsts[p];
  if constexpr (H == 4) {
    const float4 a = *(const float4*)&es[sN * 4];
    const float4 b = *(const float4*)&ed[dN * 4];
    float e0 = a.x + b.x, e1 = a.y + b.y, e2 = a.z + b.z, e3 = a.w + b.w;
    e0 = (e0 > 0.f) ? e0 : LRELU_SLOPE * e0;
    e1 = (e1 > 0.f) ? e1 : LRELU_SLOPE * e1;
    e2 = (e2 > 0.f) ? e2 : LRELU_SLOPE * e2;
    e3 = (e3 > 0.f) ? e3 : LRELU_SLOPE * e3;
    *(float4*)&exCSR[p * 4] =
        make_float4(__expf(e0), __expf(e1), __expf(e2), __expf(e3));
  } else {
    float se = 0.f, de = 0.f;
#pragma unroll
    for (int q = 0; q < 4; ++q) { se += es[q * pN + sN]; de += ed[q * pN + dN]; }
    float e = se + de;
    e = (e > 0.f) ? e : LRELU_SLOPE * e;
    exCSR[p] = __expf(e);
  }
}

// ---------------------- gather GAT aggregation + fused bias/LayerNorm(/ReLU)
template<int H, int C, bool RELU, bool BFOUT>
__global__ __launch_bounds__(256)
void gat_agg_ln(const int* __restrict__ rowptr, const int* __restrict__ srcs,
                const float* __restrict__ exCSR,
                const unsigned short* __restrict__ h,
                const float* __restrict__ bias, const float* __restrict__ lng,
                const float* __restrict__ lnb, unsigned short* __restrict__ obf,
                float* __restrict__ of32, int Nn) {
  constexpr int HC = H * C;
  constexpr int F  = HC / 64;
  const int wave = threadIdx.x >> 6;
  const int lane = threadIdx.x & 63;
  const int n = blockIdx.x * 4 + wave;
  if (n >= Nn) return;
  const int beg = rowptr[n];
  const int deg = rowptr[n + 1] - beg;
  const int hl = (lane * F) / C;

  float dsum = 0.f;
  if constexpr (H == 4) {
    for (int it = lane; it < deg * 4; it += 64) dsum += exCSR[beg * 4 + it];
#pragma unroll
    for (int off = 4; off < 64; off <<= 1) dsum += __shfl_xor(dsum, off);
    dsum = __shfl(dsum, hl);
  } else {
    for (int it = lane; it < deg; it += 64) dsum += exCSR[beg + it];
#pragma unroll
    for (int off = 1; off < 64; off <<= 1) dsum += __shfl_xor(dsum, off);
  }
  const float inv_s = 1.0f / (dsum + 1e-16f);

  float acc[F];
#pragma unroll
  for (int i = 0; i < F; ++i) acc[i] = 0.f;

  auto fma_rows = [&](const ushort4* v0, const ushort4* v1, const float* a, int cnt) {
    for (int q = 0; q < cnt; ++q) {
      acc[0] = fmaf(b2f(v0[q].x), a[q], acc[0]);
      acc[1] = fmaf(b2f(v0[q].y), a[q], acc[1]);
      acc[2] = fmaf(b2f(v0[q].z), a[q], acc[2]);
      acc[3] = fmaf(b2f(v0[q].w), a[q], acc[3]);
      if constexpr (F == 8) {
        acc[4] = fmaf(b2f(v1[q].x), a[q], acc[4]);
        acc[5] = fmaf(b2f(v1[q].y), a[q], acc[5]);
        acc[6] = fmaf(b2f(v1[q].z), a[q], acc[6]);
        acc[7] = fmaf(b2f(v1[q].w), a[q], acc[7]);
      }
    }
  };

  int j = 0;
  for (; j + 4 <= deg; j += 4) {
    int s4[4];
    float a4[4];
#pragma unroll
    for (int q = 0; q < 4; ++q) s4[q] = srcs[beg + j + q];
#pragma unroll
    for (int q = 0; q < 4; ++q) a4[q] = exCSR[(beg + j + q) * H + hl] * inv_s;
    ushort4 v0[4], v1[4];
#pragma unroll
    for (int q = 0; q < 4; ++q) {
      const unsigned short* hp = &h[(size_t)s4[q] * HC + lane * F];
      v0[q] = *(const ushort4*)hp;
      if constexpr (F == 8) v1[q] = *(const ushort4*)(hp + 4);
    }
    fma_rows(v0, v1, a4, 4);
  }
  for (; j < deg; ++j) {
    const int src = srcs[beg + j];
    const float a = exCSR[(beg + j) * H + hl] * inv_s;
    const unsigned short* hp = &h[(size_t)src * HC + lane * F];
    ushort4 v0 = *(const ushort4*)hp, v1;
    if constexpr (F == 8) v1 = *(const ushort4*)(hp + 4);
    fma_rows(&v0, &v1, &a, 1);
  }

#pragma unroll
  for (int i = 0; i < F; i += 4) {
    const float4 bb = *(const float4*)&bias[lane * F + i];
    acc[i + 0] += bb.x; acc[i + 1] += bb.y;
    acc[i + 2] += bb.z; acc[i + 3] += bb.w;
  }
  float sum = 0.f, sq = 0.f;
#pragma unroll
  for (int i = 0; i < F; ++i) { sum += acc[i]; sq += acc[i] * acc[i]; }
#pragma unroll
  for (int off = 1; off < 64; off <<= 1) {
    sum += __shfl_xor(sum, off);
    sq  += __shfl_xor(sq, off);
  }
  const float mu  = sum / HC;
  const float var = sq / HC - mu * mu;
  const float r   = rsqrtf(var + 1e-5f);
  float y[F];
#pragma unroll
  for (int i = 0; i < F; i += 4) {
    const float4 gg = *(const float4*)&lng[lane * F + i];
    const float4 bl = *(const float4*)&lnb[lane * F + i];
    y[i + 0] = (acc[i + 0] - mu) * r * gg.x + bl.x;
    y[i + 1] = (acc[i + 1] - mu) * r * gg.y + bl.y;
    y[i + 2] = (acc[i + 2] - mu) * r * gg.z + bl.z;
    y[i + 3] = (acc[i + 3] - mu) * r * gg.w + bl.w;
  }
  if constexpr (RELU) {
#pragma unroll
    for (int i = 0; i < F; ++i) y[i] = fmaxf(y[i], 0.f);
  }
  if constexpr (BFOUT) {
    unsigned short* op = &obf[(size_t)n * HC + lane * F];
    *(ushort4*)op = make_ushort4(f2b(y[0]), f2b(y[1]), f2b(y[2]), f2b(y[3]));
    if constexpr (F == 8)
      *(ushort4*)(op + 4) = make_ushort4(f2b(y[4]), f2b(y[5]), f2b(y[6]), f2b(y[7]));
  } else {
    float* op = &of32[(size_t)n * HC + lane * F];
    *(float4*)op = make_float4(y[0], y[1], y[2], y[3]);
    if constexpr (F == 8)
      *(float4*)(op + 4) = make_float4(y[4], y[5], y[6], y[7]);
  }
}

// ---------------------------------------------------------- global mean pool
__global__ __launch_bounds__(256)
void pool_partial(const unsigned short* __restrict__ x, const int* __restrict__ batch,
                  float* __restrict__ tmp, int* __restrict__ cnt, int Nn) {
  const int r0 = blockIdx.x * 64;
  const int rend = min(r0 + 64, Nn);
  const int t = threadIdx.x;
  float acc = 0.f;
  int cur = batch[r0];
  int seglen = 0;
  for (int r = r0; r < rend; ++r) {
    const int g = batch[r];
    if (g != cur) {
      unsafeAtomicAdd(&tmp[cur * 256 + t], acc);
      if (t == 0) atomicAdd(&cnt[cur], seglen);
      acc = 0.f; seglen = 0; cur = g;
    }
    acc += b2f(x[(size_t)r * 256 + t]);
    ++seglen;
  }
  unsafeAtomicAdd(&tmp[cur * 256 + t], acc);
  if (t == 0) atomicAdd(&cnt[cur], seglen);
}

__global__ __launch_bounds__(256)
void pool_final(const float* __restrict__ tmp, const int* __restrict__ cnt,
                float* __restrict__ out) {
  const int g = blockIdx.x;
  const int t = threadIdx.x;
  out[g * 256 + t] = tmp[g * 256 + t] / fmaxf((float)cnt[g], 1.f);
}

// ---------------------------------------------------------------------------
extern "C" void kernel_launch(void* const* d_in, const int* in_sizes, int n_in,
                              void* d_out, int out_size, void* d_ws, size_t ws_size,
                              hipStream_t stream) {
  const float* x    = (const float*)d_in[0];
  const int*   ei   = (const int*)d_in[1];
  const int*   batch= (const int*)d_in[2];
  const float* W1   = (const float*)d_in[3];
  const float* as1  = (const float*)d_in[4];
  const float* ad1  = (const float*)d_in[5];
  const float* b1   = (const float*)d_in[6];
  const float* g1   = (const float*)d_in[7];
  const float* be1  = (const float*)d_in[8];
  const float* W2   = (const float*)d_in[9];
  const float* as2  = (const float*)d_in[10];
  const float* ad2  = (const float*)d_in[11];
  const float* b2   = (const float*)d_in[12];
  const float* g2   = (const float*)d_in[13];
  const float* be2  = (const float*)d_in[14];

  const int N    = in_sizes[0] / 256;   // 50000
  const int E    = in_sizes[1] / 2;     // 400000
  const int Etot = E + N;
  const int Mpad = ((N + 255) / 256) * 256;   // 50176 (L2 uses BM=256)
  const int NB   = (N + 1023) / 1024;         // scan blocks (49)

  // ---------------- workspace layout ----------------
  float* ws = (float*)d_ws;
  unsigned short* out2 = (unsigned short*)ws;          // N*256 bf16
  unsigned short* A2bf = out2 + (size_t)N * 256;       // Mpad*512 bf16
  unsigned short* A1bf = A2bf;                         // Mpad*256 bf16
  unsigned short* h1bf = A2bf + (size_t)Mpad * 512;    // N*512 bf16 (h2bf aliases)
  unsigned short* W1T  = h1bf + (size_t)N * 512;       // 512*256 bf16
  unsigned short* W2T  = W1T + 512 * 256;              // 256*512 bf16
  float* es1 = (float*)(W2T + 512 * 256);              // N*4
  float* ed1 = es1 + (size_t)N * 4;                    // N*4
  float* es2 = ed1 + (size_t)N * 4;                    // 4N (per-bcol partials)
  float* ed2 = es2 + (size_t)N * 4;                    // 4N
  int* count  = (int*)(ed2 + (size_t)N * 4);           // N
  int* rowptr = count + N;                             // N+1 (+pad)
  int* cursor = rowptr + N + 4;                        // N
  int* srcs   = cursor + N;                            // Etot
  int* dsts   = srcs + Etot;                           // Etot
  float* exCSR = (float*)(dsts + Etot);                // Etot*4
  float* ptmp = exCSR + (size_t)Etot * 4;              // 64*256
  int*   pcnt = (int*)(ptmp + 64 * 256);               // 64
  int*   bsum = pcnt + 64;                             // NB
  int*   boff = bsum + 64;                             // NB
  unsigned short* h2bf = h1bf;

  const int eb = (Etot + 255) / 256;

  // ---- zero-init: es1,ed1 (8N) + es2,ed2 (8N) + count (N) contiguous ----
  hipMemsetAsync(es1, 0, (size_t)N * 17 * 4, stream);
  hipMemsetAsync(ptmp, 0, (size_t)(64 * 256 + 64) * 4, stream);
  hipMemsetAsync(A2bf + (size_t)N * 512, 0, (size_t)(Mpad - N) * 512 * 2, stream);

  // ---- prep: x->bf16 pad + degree count, weight transposes ----
  prep_x_count<<<(Mpad * 64 + 255) / 256, 256, 0, stream>>>(
      x, A1bf, N, Mpad, ei, E, Etot, count);
  cvt_wts<<<(2 * 512 * 256 + 255) / 256, 256, 0, stream>>>(W1, W2, W1T, W2T);

  // ---- CSR build ----
  scan_blocksum<<<NB, 256, 0, stream>>>(count, bsum, N);
  scan_top<<<1, 64, 0, stream>>>(bsum, boff, &rowptr[N], NB);
  scan_apply<<<NB, 256, 0, stream>>>(count, boff, rowptr, cursor, N);
  csr_scatter<<<eb, 256, 0, stream>>>(ei, E, Etot, cursor, srcs, dsts);

  // ---- layer 1: GATConv(256 -> 4x128) + LN + ReLU ----
  gemm_bres<128, 128, 2, 512, 8><<<dim3(4, Mpad / 128), 256, 0, stream>>>(
      A1bf, W1T, h1bf, N, 512, as1, ad1, es1, ed1, 4, 7, 0);
  ex_compute<4><<<eb, 256, 0, stream>>>(srcs, dsts, es1, ed1, exCSR, Etot, 0);
  gat_agg_ln<4, 128, true, true><<<(N + 3) / 4, 256, 0, stream>>>(
      rowptr, srcs, exCSR, h1bf, b1, g1, be1, A2bf, nullptr, N);

  // ---- layer 2: GATConv(512 -> 1x256) + LN ----
  gemm_bres<256, 64, 1, 1024, 16><<<dim3(4, Mpad / 256), 256, 0, stream>>>(
      A2bf, W2T, h2bf, N, 256, as2, ad2, es2, ed2, 1, 8, N);
  ex_compute<1><<<eb, 256, 0, stream>>>(srcs, dsts, es2, ed2, exCSR, Etot, N);
  gat_agg_ln<1, 256, false, true><<<(N + 3) / 4, 256, 0, stream>>>(
      rowptr, srcs, exCSR, h2bf, b2, g2, be2, out2, nullptr, N);

  // ---- global mean pool ----
  pool_partial<<<(N + 63) / 64, 256, 0, stream>>>(out2, batch, ptmp, pcnt, N);
  pool_final<<<64, 256, 0, stream>>>(ptmp, pcnt, (float*)d_out);
}

// Round 11
// 319.243 us; speedup vs baseline: 1.1333x; 1.1061x over previous
//
#include <hip/hip_runtime.h>
#include <hip/hip_bf16.h>
#include <cstdint>

#define LRELU_SLOPE 0.2f

typedef short bf16x8 __attribute__((ext_vector_type(8)));
typedef float f32x4  __attribute__((ext_vector_type(4)));

__device__ __forceinline__ float b2f(unsigned short u) {
  return __uint_as_float(((unsigned int)u) << 16);
}
__device__ __forceinline__ unsigned short f2b(float f) {  // RNE
  unsigned int u = __float_as_uint(f);
  return (unsigned short)((u + 0x7fff + ((u >> 16) & 1)) >> 16);
}

__device__ __forceinline__ void gload16(const void* g, void* l) {
  __builtin_amdgcn_global_load_lds(
      (const __attribute__((address_space(1))) unsigned int*)g,
      (__attribute__((address_space(3))) unsigned int*)l, 16, 0, 0);
}

// ---------------------------------------------- fused x->bf16 pad + csr_count
__global__ __launch_bounds__(256)
void prep_x_count(const float* __restrict__ x, unsigned short* __restrict__ o,
                  int M, int Mpad, const int* __restrict__ ei, int E, int Etot,
                  int* __restrict__ count) {
  const int i = blockIdx.x * 256 + threadIdx.x;
  if (i < Mpad * 64) {
    const int row = i >> 6;
    const int c4  = (i & 63) * 4;
    ushort4 v = make_ushort4(0, 0, 0, 0);
    if (row < M) {
      const float4 f = *(const float4*)&x[(size_t)row * 256 + c4];
      v = make_ushort4(f2b(f.x), f2b(f.y), f2b(f.z), f2b(f.w));
    }
    *(ushort4*)&o[(size_t)row * 256 + c4] = v;
  }
  if (i < Etot) {
    const int d = (i < E) ? ei[E + i] : (i - E);
    atomicAdd(&count[d], 1);
  }
}

// ------------------------------------- both weight transposes in one launch
__global__ __launch_bounds__(256)
void cvt_wts(const float* __restrict__ W1, const float* __restrict__ W2,
             unsigned short* __restrict__ W1T, unsigned short* __restrict__ W2T) {
  int j = blockIdx.x * 256 + threadIdx.x;
  if (j < 512 * 256) {
    const int n = j >> 8, k = j & 255;
    W1T[j] = f2b(W1[(size_t)k * 512 + n]);
  } else {
    j -= 512 * 256;
    const int n = j >> 9, k = j & 511;
    W2T[j] = f2b(W2[(size_t)k * 256 + n]);
  }
}

// ------------------------------------------------------------- CSR scan
__global__ __launch_bounds__(256)
void scan_blocksum(const int* __restrict__ count, int* __restrict__ bsum, int Nn) {
  const int i0 = blockIdx.x * 1024 + threadIdx.x * 4;
  int s = 0;
#pragma unroll
  for (int k = 0; k < 4; ++k) { const int i = i0 + k; if (i < Nn) s += count[i]; }
#pragma unroll
  for (int off = 1; off < 64; off <<= 1) s += __shfl_xor(s, off);
  __shared__ int ws[4];
  if ((threadIdx.x & 63) == 0) ws[threadIdx.x >> 6] = s;
  __syncthreads();
  if (threadIdx.x == 0) bsum[blockIdx.x] = ws[0] + ws[1] + ws[2] + ws[3];
}

__global__ __launch_bounds__(64)
void scan_top(const int* __restrict__ bsum, int* __restrict__ boff,
              int* __restrict__ rowptrN, int nb) {
  const int t = threadIdx.x;
  const int v = (t < nb) ? bsum[t] : 0;
  int incl = v;
#pragma unroll
  for (int off = 1; off < 64; off <<= 1) {
    const int u = __shfl_up(incl, off);
    if (t >= off) incl += u;
  }
  if (t < nb) boff[t] = incl - v;
  if (t == 63) *rowptrN = incl;
}

__global__ __launch_bounds__(256)
void scan_apply(const int* __restrict__ count, const int* __restrict__ boff,
                int* __restrict__ rowptr, int* __restrict__ cursor, int Nn) {
  const int t = threadIdx.x;
  const int lane = t & 63;
  const int w = t >> 6;
  const int i0 = blockIdx.x * 1024 + t * 4;
  int c[4]; int s = 0;
#pragma unroll
  for (int k = 0; k < 4; ++k) { const int i = i0 + k; c[k] = (i < Nn) ? count[i] : 0; s += c[k]; }
  int incl = s;
#pragma unroll
  for (int off = 1; off < 64; off <<= 1) {
    const int u = __shfl_up(incl, off);
    if (lane >= off) incl += u;
  }
  __shared__ int ws[4];
  if (lane == 63) ws[w] = incl;
  __syncthreads();
  int woff = 0;
  for (int k = 0; k < w; ++k) woff += ws[k];
  int base = boff[blockIdx.x] + woff + incl - s;
#pragma unroll
  for (int k = 0; k < 4; ++k) {
    const int i = i0 + k;
    if (i < Nn) { rowptr[i] = base; cursor[i] = base; base += c[k]; }
  }
}

__global__ __launch_bounds__(256)
void csr_scatter(const int* __restrict__ ei, int E, int Etot,
                 int* __restrict__ cursor, int* __restrict__ srcs,
                 int* __restrict__ dsts) {
  const int i = blockIdx.x * 256 + threadIdx.x;
  if (i >= Etot) return;
  const int s = (i < E) ? ei[i]     : (i - E);
  const int d = (i < E) ? ei[E + i] : (i - E);
  const int pos = atomicAdd(&cursor[d], 1);
  srcs[pos] = s;
  dsts[pos] = d;
}

// --------------- high-occupancy 64x128 bf16 MFMA GEMM + fused logit epilogue
// 2x2 waves of 32x64, BK=32, double-buffered 24 KB LDS -> 6 blocks/CU target.
template<int KSTEPS>
__global__ __launch_bounds__(256)
void gemm_bf16(const unsigned short* __restrict__ A,
               const unsigned short* __restrict__ BT,
               unsigned short* __restrict__ C, int M, int Nn, int K,
               const float* __restrict__ asrc, const float* __restrict__ adst,
               float* __restrict__ es, float* __restrict__ ed,
               int H, int lgC, int esPart) {
  __shared__ __align__(16) unsigned short smA[2][64 * 32];    // 8 KB
  __shared__ __align__(16) unsigned short smB[2][128 * 32];   // 16 KB
  const int tid  = threadIdx.x;
  const int lane = tid & 63;
  const int wid  = tid >> 6;
  const int wm = wid >> 1, wn = wid & 1;
  const int brow = blockIdx.y * 64;
  const int bcol = blockIdx.x * 128;
  const int u = lane >> 4, r15 = lane & 15;
  // staging A (1 gload16/thread): row=tid>>2 (0..63), slot=tid&3
  const int arow = tid >> 2, aslot = tid & 3;
  const size_t aBase = (size_t)(brow + arow) * K + (aslot ^ (arow & 3)) * 8;
  const int ldsA = arow * 32 + aslot * 8;
  // staging B (2 gload16/thread): chunk j: idx=j*256+tid -> row=idx>>2, slot=idx&3
  const int brow0 = tid >> 2,        bslot0 = tid & 3;
  const int brow1 = (256 + tid) >> 2, bslot1 = tid & 3;
  const size_t bBase0 = (size_t)(bcol + brow0) * K + (bslot0 ^ (brow0 & 3)) * 8;
  const size_t bBase1 = (size_t)(bcol + brow1) * K + (bslot1 ^ (brow1 & 3)) * 8;
  const int ldsB0 = brow0 * 32 + bslot0 * 8;
  const int ldsB1 = brow1 * 32 + bslot1 * 8;

  auto stage = [&](int buf, int ks) {
    const int k0 = ks * 32;
    gload16(A + aBase + k0, &smA[buf][ldsA]);
    gload16(BT + bBase0 + k0, &smB[buf][ldsB0]);
    gload16(BT + bBase1 + k0, &smB[buf][ldsB1]);
  };

  f32x4 acc[2][4] = {};
  const int sw = u ^ (r15 & 3);

  stage(0, 0);
  asm volatile("s_waitcnt vmcnt(0)" ::: "memory");
  __syncthreads();
  int cur = 0;
#pragma unroll
  for (int ks = 0; ks < KSTEPS; ++ks) {
    if (ks + 1 < KSTEPS) stage(cur ^ 1, ks + 1);
    bf16x8 af[2], bfv[4];
#pragma unroll
    for (int m = 0; m < 2; ++m) {
      const int row = wm * 32 + m * 16 + r15;
      af[m] = *(const bf16x8*)&smA[cur][row * 32 + sw * 8];
    }
#pragma unroll
    for (int n = 0; n < 4; ++n) {
      const int col = wn * 64 + n * 16 + r15;
      bfv[n] = *(const bf16x8*)&smB[cur][col * 32 + sw * 8];
    }
#pragma unroll
    for (int m = 0; m < 2; ++m)
#pragma unroll
      for (int n = 0; n < 4; ++n)
        acc[m][n] = __builtin_amdgcn_mfma_f32_16x16x32_bf16(
            af[m], bfv[n], acc[m][n], 0, 0, 0);
    if (ks + 1 < KSTEPS) {
      asm volatile("s_waitcnt vmcnt(0)" ::: "memory");
      __syncthreads();
      cur ^= 1;
    }
  }

  // ---- epilogue: acc -> LDS (bf16, pitch 128) -> coalesced 16B stores ----
  __syncthreads();
  unsigned short* cb = &smB[0][0];     // 16 KB = 64 rows x 128 cols bf16
#pragma unroll
  for (int m = 0; m < 2; ++m)
#pragma unroll
    for (int n = 0; n < 4; ++n) {
      const int col = wn * 64 + n * 16 + r15;
#pragma unroll
      for (int rr = 0; rr < 4; ++rr) {
        const int row = wm * 32 + m * 16 + u * 4 + rr;
        cb[row * 128 + col] = f2b(acc[m][n][rr]);
      }
    }
  __syncthreads();
#pragma unroll
  for (int i = 0; i < 4; ++i) {
    const int idx = (i * 256 + tid) * 8;   // ushort units, 16B per thread-chunk
    const int row = idx >> 7;              // 128 ush per row
    const int cc  = idx & 127;
    const int grow = brow + row;
    if (grow < M)
      *(float4*)&C[(size_t)grow * Nn + bcol + cc] = *(const float4*)&cb[idx];
  }

  // ---- fused attention logits: es/ed[row,head] += sum_cols h*a ----
  es += (size_t)blockIdx.x * esPart;
  ed += (size_t)blockIdx.x * esPart;
  const int head = bcol >> lgC;
  float asv[4], adv[4];
#pragma unroll
  for (int n = 0; n < 4; ++n) {
    const int cc = bcol + wn * 64 + n * 16 + r15;
    asv[n] = asrc[cc];
    adv[n] = adst[cc];
  }
#pragma unroll
  for (int m = 0; m < 2; ++m) {
#pragma unroll
    for (int rr = 0; rr < 4; ++rr) {
      float pes = 0.f, ped = 0.f;
#pragma unroll
      for (int n = 0; n < 4; ++n) {
        pes = fmaf(acc[m][n][rr], asv[n], pes);
        ped = fmaf(acc[m][n][rr], adv[n], ped);
      }
#pragma unroll
      for (int off = 1; off < 16; off <<= 1) {
        pes += __shfl_xor(pes, off);
        ped += __shfl_xor(ped, off);
      }
      if (r15 == 0) {
        const int row = brow + wm * 32 + m * 16 + u * 4 + rr;
        if (row < M) {
          unsafeAtomicAdd(&es[row * H + head], pes);
          unsafeAtomicAdd(&ed[row * H + head], ped);
        }
      }
    }
  }
}

// ------------------- edge-parallel softmax numerator (CSR order), NO atomics
template<int H>
__global__ __launch_bounds__(256)
void ex_compute(const int* __restrict__ srcs, const int* __restrict__ dsts,
                const float* __restrict__ es, const float* __restrict__ ed,
                float* __restrict__ exCSR, int Etot, int pN) {
  const int p = blockIdx.x * 256 + threadIdx.x;
  if (p >= Etot) return;
  const int sN = srcs[p], dN = dsts[p];
  if constexpr (H == 4) {
    const float4 a = *(const float4*)&es[sN * 4];
    const float4 b = *(const float4*)&ed[dN * 4];
    float e0 = a.x + b.x, e1 = a.y + b.y, e2 = a.z + b.z, e3 = a.w + b.w;
    e0 = (e0 > 0.f) ? e0 : LRELU_SLOPE * e0;
    e1 = (e1 > 0.f) ? e1 : LRELU_SLOPE * e1;
    e2 = (e2 > 0.f) ? e2 : LRELU_SLOPE * e2;
    e3 = (e3 > 0.f) ? e3 : LRELU_SLOPE * e3;
    *(float4*)&exCSR[p * 4] =
        make_float4(__expf(e0), __expf(e1), __expf(e2), __expf(e3));
  } else {
    float e = (es[sN] + es[pN + sN]) + (ed[dN] + ed[pN + dN]);
    e = (e > 0.f) ? e : LRELU_SLOPE * e;
    exCSR[p] = __expf(e);
  }
}

// ---------------------- gather GAT aggregation + fused bias/LayerNorm(/ReLU)
template<int H, int C, bool RELU, bool BFOUT>
__global__ __launch_bounds__(256)
void gat_agg_ln(const int* __restrict__ rowptr, const int* __restrict__ srcs,
                const float* __restrict__ exCSR,
                const unsigned short* __restrict__ h,
                const float* __restrict__ bias, const float* __restrict__ lng,
                const float* __restrict__ lnb, unsigned short* __restrict__ obf,
                float* __restrict__ of32, int Nn) {
  constexpr int HC = H * C;
  constexpr int F  = HC / 64;
  const int wave = threadIdx.x >> 6;
  const int lane = threadIdx.x & 63;
  const int n = blockIdx.x * 4 + wave;
  if (n >= Nn) return;
  const int beg = rowptr[n];
  const int deg = rowptr[n + 1] - beg;
  const int hl = (lane * F) / C;

  float dsum = 0.f;
  if constexpr (H == 4) {
    for (int it = lane; it < deg * 4; it += 64) dsum += exCSR[beg * 4 + it];
#pragma unroll
    for (int off = 4; off < 64; off <<= 1) dsum += __shfl_xor(dsum, off);
    dsum = __shfl(dsum, hl);
  } else {
    for (int it = lane; it < deg; it += 64) dsum += exCSR[beg + it];
#pragma unroll
    for (int off = 1; off < 64; off <<= 1) dsum += __shfl_xor(dsum, off);
  }
  const float inv_s = 1.0f / (dsum + 1e-16f);

  float acc[F];
#pragma unroll
  for (int i = 0; i < F; ++i) acc[i] = 0.f;

  auto fma_rows = [&](const ushort4* v0, const ushort4* v1, const float* a, int cnt) {
    for (int q = 0; q < cnt; ++q) {
      acc[0] = fmaf(b2f(v0[q].x), a[q], acc[0]);
      acc[1] = fmaf(b2f(v0[q].y), a[q], acc[1]);
      acc[2] = fmaf(b2f(v0[q].z), a[q], acc[2]);
      acc[3] = fmaf(b2f(v0[q].w), a[q], acc[3]);
      if constexpr (F == 8) {
        acc[4] = fmaf(b2f(v1[q].x), a[q], acc[4]);
        acc[5] = fmaf(b2f(v1[q].y), a[q], acc[5]);
        acc[6] = fmaf(b2f(v1[q].z), a[q], acc[6]);
        acc[7] = fmaf(b2f(v1[q].w), a[q], acc[7]);
      }
    }
  };

  int j = 0;
  for (; j + 4 <= deg; j += 4) {
    int s4[4];
    float a4[4];
#pragma unroll
    for (int q = 0; q < 4; ++q) s4[q] = srcs[beg + j + q];
#pragma unroll
    for (int q = 0; q < 4; ++q) a4[q] = exCSR[(beg + j + q) * H + hl] * inv_s;
    ushort4 v0[4], v1[4];
#pragma unroll
    for (int q = 0; q < 4; ++q) {
      const unsigned short* hp = &h[(size_t)s4[q] * HC + lane * F];
      v0[q] = *(const ushort4*)hp;
      if constexpr (F == 8) v1[q] = *(const ushort4*)(hp + 4);
    }
    fma_rows(v0, v1, a4, 4);
  }
  for (; j < deg; ++j) {
    const int src = srcs[beg + j];
    const float a = exCSR[(beg + j) * H + hl] * inv_s;
    const unsigned short* hp = &h[(size_t)src * HC + lane * F];
    ushort4 v0 = *(const ushort4*)hp, v1;
    if constexpr (F == 8) v1 = *(const ushort4*)(hp + 4);
    fma_rows(&v0, &v1, &a, 1);
  }

#pragma unroll
  for (int i = 0; i < F; i += 4) {
    const float4 bb = *(const float4*)&bias[lane * F + i];
    acc[i + 0] += bb.x; acc[i + 1] += bb.y;
    acc[i + 2] += bb.z; acc[i + 3] += bb.w;
  }
  float sum = 0.f, sq = 0.f;
#pragma unroll
  for (int i = 0; i < F; ++i) { sum += acc[i]; sq += acc[i] * acc[i]; }
#pragma unroll
  for (int off = 1; off < 64; off <<= 1) {
    sum += __shfl_xor(sum, off);
    sq  += __shfl_xor(sq, off);
  }
  const float mu  = sum / HC;
  const float var = sq / HC - mu * mu;
  const float r   = rsqrtf(var + 1e-5f);
  float y[F];
#pragma unroll
  for (int i = 0; i < F; i += 4) {
    const float4 gg = *(const float4*)&lng[lane * F + i];
    const float4 bl = *(const float4*)&lnb[lane * F + i];
    y[i + 0] = (acc[i + 0] - mu) * r * gg.x + bl.x;
    y[i + 1] = (acc[i + 1] - mu) * r * gg.y + bl.y;
    y[i + 2] = (acc[i + 2] - mu) * r * gg.z + bl.z;
    y[i + 3] = (acc[i + 3] - mu) * r * gg.w + bl.w;
  }
  if constexpr (RELU) {
#pragma unroll
    for (int i = 0; i < F; ++i) y[i] = fmaxf(y[i], 0.f);
  }
  if constexpr (BFOUT) {
    unsigned short* op = &obf[(size_t)n * HC + lane * F];
    *(ushort4*)op = make_ushort4(f2b(y[0]), f2b(y[1]), f2b(y[2]), f2b(y[3]));
    if constexpr (F == 8)
      *(ushort4*)(op + 4) = make_ushort4(f2b(y[4]), f2b(y[5]), f2b(y[6]), f2b(y[7]));
  } else {
    float* op = &of32[(size_t)n * HC + lane * F];
    *(float4*)op = make_float4(y[0], y[1], y[2], y[3]);
    if constexpr (F == 8)
      *(float4*)(op + 4) = make_float4(y[4], y[5], y[6], y[7]);
  }
}

// ---------------------------------------------------------- global mean pool
__global__ __launch_bounds__(256)
void pool_partial(const unsigned short* __restrict__ x, const int* __restrict__ batch,
                  float* __restrict__ tmp, int* __restrict__ cnt, int Nn) {
  const int r0 = blockIdx.x * 64;
  const int rend = min(r0 + 64, Nn);
  const int t = threadIdx.x;
  float acc = 0.f;
  int cur = batch[r0];
  int seglen = 0;
  for (int r = r0; r < rend; ++r) {
    const int g = batch[r];
    if (g != cur) {
      unsafeAtomicAdd(&tmp[cur * 256 + t], acc);
      if (t == 0) atomicAdd(&cnt[cur], seglen);
      acc = 0.f; seglen = 0; cur = g;
    }
    acc += b2f(x[(size_t)r * 256 + t]);
    ++seglen;
  }
  unsafeAtomicAdd(&tmp[cur * 256 + t], acc);
  if (t == 0) atomicAdd(&cnt[cur], seglen);
}

__global__ __launch_bounds__(256)
void pool_final(const float* __restrict__ tmp, const int* __restrict__ cnt,
                float* __restrict__ out) {
  const int g = blockIdx.x;
  const int t = threadIdx.x;
  out[g * 256 + t] = tmp[g * 256 + t] / fmaxf((float)cnt[g], 1.f);
}

// ---------------------------------------------------------------------------
extern "C" void kernel_launch(void* const* d_in, const int* in_sizes, int n_in,
                              void* d_out, int out_size, void* d_ws, size_t ws_size,
                              hipStream_t stream) {
  const float* x    = (const float*)d_in[0];
  const int*   ei   = (const int*)d_in[1];
  const int*   batch= (const int*)d_in[2];
  const float* W1   = (const float*)d_in[3];
  const float* as1  = (const float*)d_in[4];
  const float* ad1  = (const float*)d_in[5];
  const float* b1   = (const float*)d_in[6];
  const float* g1   = (const float*)d_in[7];
  const float* be1  = (const float*)d_in[8];
  const float* W2   = (const float*)d_in[9];
  const float* as2  = (const float*)d_in[10];
  const float* ad2  = (const float*)d_in[11];
  const float* b2   = (const float*)d_in[12];
  const float* g2   = (const float*)d_in[13];
  const float* be2  = (const float*)d_in[14];

  const int N    = in_sizes[0] / 256;   // 50000
  const int E    = in_sizes[1] / 2;     // 400000
  const int Etot = E + N;
  const int Mpad = ((N + 63) / 64) * 64;      // 50048
  const int NB   = (N + 1023) / 1024;         // scan blocks (49)

  // ---------------- workspace layout ----------------
  float* ws = (float*)d_ws;
  unsigned short* out2 = (unsigned short*)ws;          // N*256 bf16
  unsigned short* A2bf = out2 + (size_t)N * 256;       // Mpad*512 bf16
  unsigned short* A1bf = A2bf;                         // Mpad*256 bf16
  unsigned short* h1bf = A2bf + (size_t)Mpad * 512;    // N*512 bf16 (h2bf aliases)
  unsigned short* W1T  = h1bf + (size_t)N * 512;       // 512*256 bf16
  unsigned short* W2T  = W1T + 512 * 256;              // 256*512 bf16
  float* es1 = (float*)(W2T + 512 * 256);              // N*4
  float* ed1 = es1 + (size_t)N * 4;                    // N*4
  float* es2 = ed1 + (size_t)N * 4;                    // 2N (per-bcol partials)
  float* ed2 = es2 + (size_t)N * 2;                    // 2N
  int* count  = (int*)(ed2 + (size_t)N * 2);           // N
  int* rowptr = count + N;                             // N+1 (+pad)
  int* cursor = rowptr + N + 4;                        // N
  int* srcs   = cursor + N;                            // Etot
  int* dsts   = srcs + Etot;                           // Etot
  float* exCSR = (float*)(dsts + Etot);                // Etot*4
  float* ptmp = exCSR + (size_t)Etot * 4;              // 64*256
  int*   pcnt = (int*)(ptmp + 64 * 256);               // 64
  int*   bsum = pcnt + 64;                             // NB
  int*   boff = bsum + 64;                             // NB
  unsigned short* h2bf = h1bf;

  const int eb = (Etot + 255) / 256;

  // ---- zero-init: es1,ed1 (8N) + es2,ed2 (4N) + count (N) contiguous ----
  hipMemsetAsync(es1, 0, (size_t)N * 13 * 4, stream);
  hipMemsetAsync(ptmp, 0, (size_t)(64 * 256 + 64) * 4, stream);
  hipMemsetAsync(A2bf + (size_t)N * 512, 0, (size_t)(Mpad - N) * 512 * 2, stream);

  // ---- prep: x->bf16 pad + degree count, weight transposes ----
  prep_x_count<<<(Mpad * 64 + 255) / 256, 256, 0, stream>>>(
      x, A1bf, N, Mpad, ei, E, Etot, count);
  cvt_wts<<<(2 * 512 * 256 + 255) / 256, 256, 0, stream>>>(W1, W2, W1T, W2T);

  // ---- CSR build ----
  scan_blocksum<<<NB, 256, 0, stream>>>(count, bsum, N);
  scan_top<<<1, 64, 0, stream>>>(bsum, boff, &rowptr[N], NB);
  scan_apply<<<NB, 256, 0, stream>>>(count, boff, rowptr, cursor, N);
  csr_scatter<<<eb, 256, 0, stream>>>(ei, E, Etot, cursor, srcs, dsts);

  // ---- layer 1: GATConv(256 -> 4x128) + LN + ReLU ----
  gemm_bf16<8><<<dim3(4, Mpad / 64), 256, 0, stream>>>(
      A1bf, W1T, h1bf, N, 512, 256, as1, ad1, es1, ed1, 4, 7, 0);
  ex_compute<4><<<eb, 256, 0, stream>>>(srcs, dsts, es1, ed1, exCSR, Etot, 0);
  gat_agg_ln<4, 128, true, true><<<(N + 3) / 4, 256, 0, stream>>>(
      rowptr, srcs, exCSR, h1bf, b1, g1, be1, A2bf, nullptr, N);

  // ---- layer 2: GATConv(512 -> 1x256) + LN ----
  gemm_bf16<16><<<dim3(2, Mpad / 64), 256, 0, stream>>>(
      A2bf, W2T, h2bf, N, 256, 512, as2, ad2, es2, ed2, 1, 8, N);
  ex_compute<1><<<eb, 256, 0, stream>>>(srcs, dsts, es2, ed2, exCSR, Etot, N);
  gat_agg_ln<1, 256, false, true><<<(N + 3) / 4, 256, 0, stream>>>(
      rowptr, srcs, exCSR, h2bf, b2, g2, be2, out2, nullptr, N);

  // ---- global mean pool ----
  pool_partial<<<(N + 63) / 64, 256, 0, stream>>>(out2, batch, ptmp, pcnt, N);
  pool_final<<<64, 256, 0, stream>>>(ptmp, pcnt, (float*)d_out);
}